// Round 1
// baseline (2520.154 us; speedup 1.0000x reference)
//
#include <hip/hip_runtime.h>
#include <hip/hip_bf16.h>
#include <math.h>

#define NFEAT 500
#define NHID  256
#define NCLS  64
#define KPOLY 10

// ------------------------- weight transposes -------------------------
__global__ void transpose_w1(const float* __restrict__ W1, float* __restrict__ W1T) {
  int idx = blockIdx.x * blockDim.x + threadIdx.x;   // W1T[k*256 + h] = W1[h*500 + k]
  if (idx >= NFEAT * NHID) return;
  int k = idx / NHID, h = idx % NHID;
  W1T[idx] = W1[h * NFEAT + k];
}
__global__ void transpose_w2(const float* __restrict__ W2, float* __restrict__ W2T) {
  int idx = blockIdx.x * blockDim.x + threadIdx.x;   // W2T[k*64 + c] = W2[c*256 + k]
  if (idx >= NHID * NCLS) return;
  int k = idx / NCLS, c = idx % NCLS;
  W2T[idx] = W2[c * NHID + k];
}

// ------------------------- CSR build -------------------------
__global__ void edge_count(const int* __restrict__ ei, int E,
                           int* __restrict__ deg, int* __restrict__ cnt) {
  int stride = gridDim.x * blockDim.x;
  for (int e = blockIdx.x * blockDim.x + threadIdx.x; e < E; e += stride) {
    int r = ei[e], c = ei[E + e];
    atomicAdd(&cnt[r], 1);              // all edges go in CSR (self-loops get w=0)
    if (r != c) atomicAdd(&deg[r], 1);  // valid-degree for Laplacian
  }
}

__global__ void make_dinv(const int* __restrict__ deg, float* __restrict__ dinv, int n) {
  int i = blockIdx.x * blockDim.x + threadIdx.x;
  if (i < n) {
    int d = deg[i];
    dinv[i] = (d > 0) ? rsqrtf((float)d) : 0.0f;
  }
}

__global__ void scan_block(const int* __restrict__ cnt, int* __restrict__ rowptr,
                           int* __restrict__ bsums, int n) {
  __shared__ int s[256];
  int i = blockIdx.x * 256 + threadIdx.x;
  int v = (i < n) ? cnt[i] : 0;
  s[threadIdx.x] = v;
  __syncthreads();
  for (int off = 1; off < 256; off <<= 1) {
    int t = (threadIdx.x >= (unsigned)off) ? s[threadIdx.x - off] : 0;
    __syncthreads();
    s[threadIdx.x] += t;
    __syncthreads();
  }
  if (i < n) rowptr[i + 1] = s[threadIdx.x];
  if (threadIdx.x == 255) bsums[blockIdx.x] = s[255];
}

__global__ void scan_sums(int* __restrict__ bsums, int nb, int* __restrict__ rowptr) {
  if (threadIdx.x == 0 && blockIdx.x == 0) {
    int run = 0;
    for (int b = 0; b < nb; ++b) { int t = bsums[b]; bsums[b] = run; run += t; }
    rowptr[0] = 0;
  }
}

__global__ void scan_add(int* __restrict__ rowptr, const int* __restrict__ bsums, int n) {
  int i = blockIdx.x * 256 + threadIdx.x;
  if (i < n) rowptr[i + 1] += bsums[i >> 8];
}

__global__ void scatter_edges(const int* __restrict__ ei, int E,
                              const float* __restrict__ dinv,
                              const int* __restrict__ rowptr, int* __restrict__ cur,
                              int* __restrict__ colc, float* __restrict__ wcsr) {
  int stride = gridDim.x * blockDim.x;
  for (int e = blockIdx.x * blockDim.x + threadIdx.x; e < E; e += stride) {
    int r = ei[e], c = ei[E + e];
    int pos = rowptr[r] + atomicAdd(&cur[r], 1);
    colc[pos] = c;
    wcsr[pos] = (r != c) ? (-dinv[r] * dinv[c]) : 0.0f;
  }
}

// ------------------------- fused MLP: h2 = relu(x@W1^T)@W2^T -------------------------
// block = 256 threads, 32 rows/block. GEMM1 register tile 4x8 per thread.
__global__ __launch_bounds__(256, 2) void mlp_fused(
    const float* __restrict__ x, const float* __restrict__ W1T,
    const float* __restrict__ W2T, float* __restrict__ h2, int n)
{
  __shared__ float hs[32][257];       // relu(h) tile, +1 pad vs 32-way conflicts
  __shared__ float xs[32][20];        // x chunk [row][k]
  __shared__ float ws1[20][256];      // W1T chunk [k][hid]
  __shared__ float w2s[64][64];       // W2T chunk [k][cls]

  const int tid = threadIdx.x;
  const int tx = tid & 31;            // hidden group: 8 hiddens each
  const int ty = tid >> 5;            // row group: 4 rows each
  const int row0 = blockIdx.x * 32;

  float acc[4][8];
#pragma unroll
  for (int i = 0; i < 4; ++i)
#pragma unroll
    for (int j = 0; j < 8; ++j) acc[i][j] = 0.0f;

  for (int k0 = 0; k0 < NFEAT; k0 += 20) {
    // stage x tile (32x20 = 640 elements)
    for (int idx = tid; idx < 32 * 20; idx += 256) {
      int m = idx / 20, kk = idx % 20;
      int r = row0 + m;
      xs[m][kk] = (r < n) ? x[(size_t)r * NFEAT + k0 + kk] : 0.0f;
    }
    // stage W1T tile (20x256), coalesced
#pragma unroll
    for (int j = 0; j < 20; ++j) ws1[j][tid] = W1T[(k0 + j) * NHID + tid];
    __syncthreads();

#pragma unroll
    for (int kk = 0; kk < 20; ++kk) {
      float a[4];
#pragma unroll
      for (int i = 0; i < 4; ++i) a[i] = xs[ty * 4 + i][kk];
      float4 b0 = *(const float4*)&ws1[kk][tx * 8];
      float4 b1 = *(const float4*)&ws1[kk][tx * 8 + 4];
      float b[8] = {b0.x, b0.y, b0.z, b0.w, b1.x, b1.y, b1.z, b1.w};
#pragma unroll
      for (int i = 0; i < 4; ++i)
#pragma unroll
        for (int j = 0; j < 8; ++j) acc[i][j] = fmaf(a[i], b[j], acc[i][j]);
    }
    __syncthreads();
  }

  // relu -> hs
#pragma unroll
  for (int i = 0; i < 4; ++i) {
    int r = ty * 4 + i;
#pragma unroll
    for (int j = 0; j < 8; ++j) hs[r][tx * 8 + j] = fmaxf(acc[i][j], 0.0f);
  }
  __syncthreads();

  // GEMM2: out[32][64] = hs @ W2T
  const int cx = tid & 15;            // 4 classes each
  const int ry = tid >> 4;            // 2 rows each
  float o[2][4];
#pragma unroll
  for (int i = 0; i < 2; ++i)
#pragma unroll
    for (int j = 0; j < 4; ++j) o[i][j] = 0.0f;

  for (int kb = 0; kb < NHID; kb += 64) {
    for (int idx = tid; idx < 64 * 64; idx += 256)
      ((float*)w2s)[idx] = W2T[kb * NCLS + idx];
    __syncthreads();
#pragma unroll
    for (int kk = 0; kk < 64; ++kk) {
      float a0 = hs[ry * 2 + 0][kb + kk];
      float a1 = hs[ry * 2 + 1][kb + kk];
      float4 bb = *(const float4*)&w2s[kk][cx * 4];
      o[0][0] = fmaf(a0, bb.x, o[0][0]); o[0][1] = fmaf(a0, bb.y, o[0][1]);
      o[0][2] = fmaf(a0, bb.z, o[0][2]); o[0][3] = fmaf(a0, bb.w, o[0][3]);
      o[1][0] = fmaf(a1, bb.x, o[1][0]); o[1][1] = fmaf(a1, bb.y, o[1][1]);
      o[1][2] = fmaf(a1, bb.z, o[1][2]); o[1][3] = fmaf(a1, bb.w, o[1][3]);
    }
    __syncthreads();
  }
#pragma unroll
  for (int i = 0; i < 2; ++i) {
    int r = row0 + ry * 2 + i;
    if (r < n)
      *(float4*)&h2[(size_t)r * NCLS + cx * 4] = make_float4(o[i][0], o[i][1], o[i][2], o[i][3]);
  }
}

// ------------------------- SpMM (wave per row, lane = channel) -------------------------
__global__ void spmm_first(const int* __restrict__ rowptr, const int* __restrict__ colc,
                           const float* __restrict__ wcsr, const float* __restrict__ h,
                           float* __restrict__ tx1, float* __restrict__ acc,
                           const float* __restrict__ cw, int n) {
  int wid = (blockIdx.x * blockDim.x + threadIdx.x) >> 6;
  int lane = threadIdx.x & 63;
  if (wid >= n) return;
  int e0 = rowptr[wid], e1 = rowptr[wid + 1];
  float s = 0.0f;
  for (int e = e0; e < e1; ++e) {
    int c = colc[e];
    float wt = wcsr[e];
    s = fmaf(wt, h[(size_t)c * NCLS + lane], s);
  }
  size_t idx = (size_t)wid * NCLS + lane;
  tx1[idx] = s;
  acc[idx] = cw[0] * h[idx] + cw[1] * s;
}

__global__ void spmm_step(const int* __restrict__ rowptr, const int* __restrict__ colc,
                          const float* __restrict__ wcsr, const float* __restrict__ curb,
                          const float* __restrict__ prevb, float* __restrict__ nextb,
                          float* __restrict__ acc, const float* __restrict__ cw,
                          int k, int n) {
  int wid = (blockIdx.x * blockDim.x + threadIdx.x) >> 6;
  int lane = threadIdx.x & 63;
  if (wid >= n) return;
  int e0 = rowptr[wid], e1 = rowptr[wid + 1];
  float s = 0.0f;
  for (int e = e0; e < e1; ++e) {
    int c = colc[e];
    float wt = wcsr[e];
    s = fmaf(wt, curb[(size_t)c * NCLS + lane], s);
  }
  size_t idx = (size_t)wid * NCLS + lane;
  float t2 = 2.0f * s - prevb[idx];
  nextb[idx] = t2;
  acc[idx] += cw[k] * t2;
}

// ------------------------- log-softmax over 64 classes (in-place) -------------------------
__global__ void log_softmax_k(float* __restrict__ io, int n) {
  int wid = (blockIdx.x * blockDim.x + threadIdx.x) >> 6;
  int lane = threadIdx.x & 63;
  if (wid >= n) return;
  size_t idx = (size_t)wid * NCLS + lane;
  float v = io[idx];
  float m = v;
#pragma unroll
  for (int off = 32; off > 0; off >>= 1) m = fmaxf(m, __shfl_xor(m, off, 64));
  float ex = expf(v - m);
  float ssum = ex;
#pragma unroll
  for (int off = 32; off > 0; off >>= 1) ssum += __shfl_xor(ssum, off, 64);
  io[idx] = v - m - logf(ssum);
}

// ------------------------- launch -------------------------
extern "C" void kernel_launch(void* const* d_in, const int* in_sizes, int n_in,
                              void* d_out, int out_size, void* d_ws, size_t ws_size,
                              hipStream_t stream) {
  const float* x  = (const float*)d_in[0];
  const int*   ei = (const int*)d_in[1];
  const float* W1 = (const float*)d_in[2];
  const float* W2 = (const float*)d_in[3];
  const float* cw = (const float*)d_in[4];
  float* out = (float*)d_out;

  const int n = in_sizes[0] / NFEAT;     // 100000
  const int E = in_sizes[1] / 2;         // 1600000

  // workspace carve-up (256B aligned)
  size_t off = 0;
  auto alloc = [&](size_t bytes) { size_t o = off; off += (bytes + 255) & ~(size_t)255; return o; };
  char* w = (char*)d_ws;
  size_t o_deg   = alloc((size_t)n * 4);
  size_t o_cnt   = alloc((size_t)n * 4);
  size_t o_cur   = alloc((size_t)n * 4);
  size_t o_dinv  = alloc((size_t)n * 4);
  size_t o_rp    = alloc((size_t)(n + 1) * 4);
  size_t o_bs    = alloc(4096 * 4);
  size_t o_w1t   = alloc((size_t)NFEAT * NHID * 4);
  size_t o_w2t   = alloc((size_t)NHID * NCLS * 4);
  size_t o_colc  = alloc((size_t)E * 4);
  size_t o_wcsr  = alloc((size_t)E * 4);
  size_t o_bufH  = alloc((size_t)n * NCLS * 4);
  size_t o_bufA  = alloc((size_t)n * NCLS * 4);
  size_t o_bufB  = alloc((size_t)n * NCLS * 4);

  int*   deg    = (int*)(w + o_deg);
  int*   cnt    = (int*)(w + o_cnt);
  int*   curi   = (int*)(w + o_cur);
  float* dinv   = (float*)(w + o_dinv);
  int*   rowptr = (int*)(w + o_rp);
  int*   bsums  = (int*)(w + o_bs);
  float* W1T    = (float*)(w + o_w1t);
  float* W2T    = (float*)(w + o_w2t);
  int*   colc   = (int*)(w + o_colc);
  float* wcsr   = (float*)(w + o_wcsr);
  float* bufH   = (float*)(w + o_bufH);
  float* bufA   = (float*)(w + o_bufA);
  float* bufB   = (float*)(w + o_bufB);

  // zero deg/cnt/cur (contiguous region incl. padding)
  hipMemsetAsync(w + o_deg, 0, o_dinv - o_deg, stream);

  const int nb = (n + 255) / 256;

  transpose_w1<<<(NFEAT * NHID + 255) / 256, 256, 0, stream>>>(W1, W1T);
  transpose_w2<<<(NHID * NCLS + 255) / 256, 256, 0, stream>>>(W2, W2T);

  edge_count<<<1024, 256, 0, stream>>>(ei, E, deg, cnt);
  make_dinv<<<nb, 256, 0, stream>>>(deg, dinv, n);
  scan_block<<<nb, 256, 0, stream>>>(cnt, rowptr, bsums, n);
  scan_sums<<<1, 1, 0, stream>>>(bsums, nb, rowptr);
  scan_add<<<nb, 256, 0, stream>>>(rowptr, bsums, n);
  scatter_edges<<<1024, 256, 0, stream>>>(ei, E, dinv, rowptr, curi, colc, wcsr);

  mlp_fused<<<(n + 31) / 32, 256, 0, stream>>>(x, W1T, W2T, bufH, n);

  const int spmm_blocks = (n + 3) / 4;   // 4 waves per 256-thread block
  spmm_first<<<spmm_blocks, 256, 0, stream>>>(rowptr, colc, wcsr, bufH, bufA, out, cw, n);

  float* P = bufH;  // Tx_{k-2}
  float* C = bufA;  // Tx_{k-1}
  float* N = bufB;  // Tx_k (to write)
  for (int k = 2; k <= KPOLY; ++k) {
    spmm_step<<<spmm_blocks, 256, 0, stream>>>(rowptr, colc, wcsr, C, P, N, out, cw, k, n);
    float* t = P; P = C; C = N; N = t;
  }

  log_softmax_k<<<spmm_blocks, 256, 0, stream>>>(out, n);
}